// Round 8
// baseline (234.265 us; speedup 1.0000x reference)
//
#include <hip/hip_runtime.h>
#include <hip/hip_bf16.h>
#include <math.h>

#define B_ 32
#define T_ 2000
#define DE_ 512
#define DD_ 1024
#define A_ 128
#define FN_ 32
#define FS_ 16
#define KW_ (2*FS_+1)   // 33

typedef __bf16 bf16x8 __attribute__((ext_vector_type(8)));
typedef __bf16 bf16x4 __attribute__((ext_vector_type(4)));
typedef float f32x4 __attribute__((ext_vector_type(4)));

#define BT 64            // t-rows per score block
#define KC 32            // K columns per staged chunk (16 iterations)
#define LSTR 40          // loc tile LDS stride (bf16)

// async global->LDS, 16 B per lane; dest = lds base (wave-uniform) + lane*16
__device__ __forceinline__ void load_lds16(const void* g, void* l) {
    __builtin_amdgcn_global_load_lds(
        (const __attribute__((address_space(1))) unsigned int*)g,
        (__attribute__((address_space(3))) unsigned int*)l, 16, 0, 0);
}

__device__ __forceinline__ bf16x8 cvt8v(f32x4 x, f32x4 y) {
    bf16x8 o;
    o[0] = (__bf16)x[0]; o[1] = (__bf16)x[1]; o[2] = (__bf16)x[2]; o[3] = (__bf16)x[3];
    o[4] = (__bf16)y[0]; o[5] = (__bf16)y[1]; o[6] = (__bf16)y[2]; o[7] = (__bf16)y[3];
    return o;
}

// ---------------------------------------------------------------------------
// Kernel 1: prep.
//  blocks   0..63 : enc_w/att_w fp32->bf16
//  blocks  64..191: pdec[b][a] = att_b[a] + input_dec[b] . dec_w[a]
//  blocks 192..208: zero ctx_un (16384 f) + denom (32 f)
// ---------------------------------------------------------------------------
__global__ __launch_bounds__(256) void prep_kernel(
    const float* __restrict__ enc_w, const float* __restrict__ att_w,
    const float* __restrict__ input_dec, const float* __restrict__ dec_w,
    const float* __restrict__ att_b,
    __bf16* __restrict__ enc_bf, __bf16* __restrict__ att_bf,
    float* __restrict__ pdec, float* __restrict__ ctx_un /* denom follows */)
{
    int bx = blockIdx.x, tid = threadIdx.x;
    if (bx < 64) {
        int i = bx * 256 + tid;                         // float4 index
        float4 v = ((const float4*)enc_w)[i];
        bf16x4 o;
        o[0] = (__bf16)v.x; o[1] = (__bf16)v.y; o[2] = (__bf16)v.z; o[3] = (__bf16)v.w;
        *(bf16x4*)(enc_bf + (size_t)i * 4) = o;
        if (i < (A_ * FN_) / 4) {
            float4 w = ((const float4*)att_w)[i];
            bf16x4 p;
            p[0] = (__bf16)w.x; p[1] = (__bf16)w.y; p[2] = (__bf16)w.z; p[3] = (__bf16)w.w;
            *(bf16x4*)(att_bf + (size_t)i * 4) = p;
        }
    } else if (bx < 192) {
        int pb = bx - 64;                               // 0..127
        int b  = pb >> 2;
        int a0 = (pb & 3) * 32;
        int al = tid >> 3;                              // 0..31
        int kg = tid & 7;                               // 0..7
        int a  = a0 + al;
        const float4* w = (const float4*)(dec_w + (size_t)a * DD_);
        const float4* x = (const float4*)(input_dec + (size_t)b * DD_);
        float acc = 0.f;
        #pragma unroll 8
        for (int j = 0; j < 32; j++) {
            int i4 = kg + j * 8;
            float4 wv = w[i4], xv = x[i4];
            acc += wv.x * xv.x + wv.y * xv.y + wv.z * xv.z + wv.w * xv.w;
        }
        acc += __shfl_xor(acc, 1, 64);
        acc += __shfl_xor(acc, 2, 64);
        acc += __shfl_xor(acc, 4, 64);
        if (kg == 0) pdec[b * A_ + a] = acc + att_b[a];
    } else {
        int idx = (bx - 192) * 256 + tid;               // float4 index
        if (idx < (B_ * DE_ + B_) / 4 + 1)              // 16416 floats -> 4104 f4
            ((float4*)ctx_un)[idx] = make_float4(0.f, 0.f, 0.f, 0.f);
    }
}

// ---------------------------------------------------------------------------
// Kernel 2: score + context partials. One block = (b, 64 t-rows), 256 thr.
// ASYMMETRIC pipeline depth matched to latency source.
// A (input_enc, HBM ~900cyc) -> 3 rotating buffers, issued 3 iters ahead
// (~750cyc cover). B (enc_bf, L2-hot ~200cyc) -> 2 buffers, 2 iters ahead.
// Counted waits (full-unroll, compile-time): steady vmcnt(6); tail 4 / 0.
// LDS 46 KB -> 3 blocks/CU; 256 of 1024 blocks queue behind finishers ->
// quasi-dynamic load balance (masked blocks early-exit and free slots).
// Both operands staged via global_load_lds (cannot be register-sunk).
// K accumulation order unchanged -> bit-identical output.
// Max-free softmax: w = exp(score - M), M = sum|out_w|. Block accumulates
// its 64x512 tile into ctx_un + denom.
// ---------------------------------------------------------------------------
__global__ __launch_bounds__(256, 3) void score_kernel(
    const float* __restrict__ input_enc, const __bf16* __restrict__ enc_bf,
    const float* __restrict__ prev_att,  const float* __restrict__ conv_w,
    const __bf16* __restrict__ att_bf,   const float* __restrict__ pdec,
    const float* __restrict__ out_w,     const int* __restrict__ lengths,
    float* __restrict__ wbuf, float* __restrict__ ctx_un,
    float* __restrict__ denom)
{
    __shared__ __align__(16) char At3[3][8192];  // A bufs: 64 rows x 32 f32 (128B/row, XOR-8 swz)
    __shared__ __align__(16) char Bt2[2][8192];  // B bufs: 128 rows x 32 bf16 (64B/row, XOR swz)
    __shared__ __align__(16) float pa_s[BT + 2 * FS_];
    __shared__ __align__(16) __bf16 loc_s[BT * LSTR];
    __shared__ float w_s[BT];

    const int tid  = threadIdx.x;
    const int lane = tid & 63;
    const int wv   = tid >> 6;
    const int b  = blockIdx.y;
    const int t0 = blockIdx.x * BT;
    const int len = lengths[b];

    // ---- early exit: block entirely past this utterance's length ----
    if (t0 >= len) {
        if (tid < BT) {
            int t = t0 + tid;
            if (t < T_) wbuf[b * T_ + t] = 0.f;
        }
        return;
    }

    // ---- DMA issue: 2 A-loads / 2 B-loads per thread per chunk ----
    auto issueA = [&](int kc, int bufi) {
        #pragma unroll
        for (int j = 0; j < 2; j++) {
            int s  = j * 256 + tid;              // 0..511
            int r  = s >> 3;                     // row 0..63 (8 x 16B slots/row)
            int q  = s & 7;                      // phys 16B slot
            int cl = q ^ (r & 7);                // XOR-8 swizzle (source side)
            int t  = t0 + r; if (t > T_ - 1) t = T_ - 1;
            load_lds16(input_enc + ((size_t)(b * T_ + t)) * DE_ + kc + cl * 4,
                       At3[bufi] + j * 4096 + wv * 1024);
        }
    };
    auto issueB = [&](int kc, int bufi) {
        #pragma unroll
        for (int j = 0; j < 2; j++) {
            int s  = j * 256 + tid;              // 0..511
            int r  = s >> 2;                     // row 0..127 (4 x 16B slots/row)
            int q  = s & 3;                      // phys slot
            int cl = q ^ ((r >> 1) & 3);         // swizzle: 2-way max conflict on read
            load_lds16(enc_bf + (size_t)r * DE_ + kc + cl * 8,
                       Bt2[bufi] + j * 4096 + wv * 1024);
        }
    };

    // prologue: fill A0,A1,A2 and B0,B1 (latency covered by pa/conv phase)
    issueA(0 * KC, 0);  issueB(0 * KC, 0);
    issueA(1 * KC, 1);  issueB(1 * KC, 1);
    issueA(2 * KC, 2);

    // conv weights for this thread's filter f: direct from global (L1-hot)
    const int f    = tid & 31;
    const int rblk = tid >> 5;                   // 0..7 -> rows rblk*8..rblk*8+7
    float cwr[KW_];
    #pragma unroll
    for (int k = 0; k < KW_; k++) cwr[k] = conv_w[f * KW_ + k];

    if (tid < BT + 2 * FS_) {
        int t = t0 - FS_ + tid;
        pa_s[tid] = (t >= 0 && t < T_) ? prev_att[b * T_ + t] : 0.f;
    }
    __syncthreads();                             // pa_s ready (drains prologue DMAs)

    {   // conv -> loc (bf16), register-blocked: 8 consecutive rows per thread
        float par[40];
        #pragma unroll
        for (int j = 0; j < 10; j++)
            *(float4*)&par[j * 4] = *(const float4*)&pa_s[rblk * 8 + j * 4];
        float accv[8] = {0.f, 0.f, 0.f, 0.f, 0.f, 0.f, 0.f, 0.f};
        #pragma unroll
        for (int k = 0; k < KW_; k++) {
            float c = cwr[k];
            #pragma unroll
            for (int j = 0; j < 8; j++) accv[j] += par[j + k] * c;
        }
        #pragma unroll
        for (int j = 0; j < 8; j++)
            loc_s[(rblk * 8 + j) * LSTR + f] = (__bf16)accv[j];
    }
    __syncthreads();                             // loc_s ready

    const int col  = lane & 15;
    const int grp  = lane >> 4;
    const int rowb = wv * 16 + col;              // 0..63
    const int keyA = rowb & 7;                   // A-read swizzle key

    f32x4 acc[8];
    const f32x4 zero = (f32x4){0.f, 0.f, 0.f, 0.f};

    {   // loc-projection MFMA (K=32=FN)
        bf16x8 afrag = *(const bf16x8*)(loc_s + rowb * LSTR + grp * 8);
        #pragma unroll
        for (int i = 0; i < 8; i++) {
            bf16x8 bfrag = *(const bf16x8*)(att_bf + (size_t)(i * 16 + col) * FN_ + grp * 8);
            acc[i] = __builtin_amdgcn_mfma_f32_16x16x32_bf16(afrag, bfrag, zero, 0, 0, 0);
        }
    }

    auto compute = [&](const char* Ab, const char* Bb) {
        f32x4 v0 = *(const f32x4*)(Ab + rowb * 128 + ((grp * 2)     ^ keyA) * 16);
        f32x4 v1 = *(const f32x4*)(Ab + rowb * 128 + ((grp * 2 + 1) ^ keyA) * 16);
        bf16x8 af = cvt8v(v0, v1);               // cols kc+grp*8 .. +8
        #pragma unroll
        for (int i = 0; i < 8; i++) {
            int row = i * 16 + col;
            bf16x8 bfrag = *(const bf16x8*)(Bb + row * 64 + ((grp ^ ((row >> 1) & 3)) * 16));
            acc[i] = __builtin_amdgcn_mfma_f32_16x16x32_bf16(af, bfrag, acc[i], 0, 0, 0);
        }
    };

    // ---- K-loop: A 3-deep / B 2-deep global_load_lds pipeline, counted vmcnt
    // FIFO at wait of iter it (steady): {A(it+1),B(it+1),A(it+2),B(it+2),A(it+3)}
    // = 10 ops; retire oldest 4 -> vmcnt(6). Tail: it=13 -> 4, it=14 -> 0.
    #pragma unroll
    for (int it = 0; it < 16; ++it) {
        compute(At3[it % 3], Bt2[it & 1]);
        if (it == 15) break;
        __builtin_amdgcn_s_barrier();            // all waves done reading bufs of it
        if (it + 2 <= 15) issueB((it + 2) * KC, (it + 2) & 1);
        if (it + 3 <= 15) issueA((it + 3) * KC, (it + 3) % 3);
        if (it <= 12)      asm volatile("s_waitcnt vmcnt(6)" ::: "memory");
        else if (it == 13) asm volatile("s_waitcnt vmcnt(4)" ::: "memory");
        else               asm volatile("s_waitcnt vmcnt(0)" ::: "memory");
        __builtin_amdgcn_s_barrier();            // bufs of it+1 visible to all
    }

    // epilogue: s = tanh(acc + bias) . out_w over a; M = sum|out_w|
    float s[4] = {0.f, 0.f, 0.f, 0.f};
    float Mabs = 0.f;
    #pragma unroll
    for (int i = 0; i < 8; i++) {
        int a = i * 16 + col;
        float ow = out_w[a];
        Mabs += fabsf(ow);
        float bias = pdec[b * A_ + a];
        #pragma unroll
        for (int r = 0; r < 4; r++) {
            float v = acc[i][r] + bias;
            v = fminf(fmaxf(v, -15.f), 15.f);
            float e = __expf(2.f * v);
            s[r] += ow * ((e - 1.f) / (e + 1.f));
        }
    }
    #pragma unroll
    for (int r = 0; r < 4; r++) {
        s[r] += __shfl_xor(s[r], 1, 64);
        s[r] += __shfl_xor(s[r], 2, 64);
        s[r] += __shfl_xor(s[r], 4, 64);
        s[r] += __shfl_xor(s[r], 8, 64);
    }
    Mabs += __shfl_xor(Mabs, 1, 64);
    Mabs += __shfl_xor(Mabs, 2, 64);
    Mabs += __shfl_xor(Mabs, 4, 64);
    Mabs += __shfl_xor(Mabs, 8, 64);    // same value & rounding in every wave

    if (col == 0) {
        #pragma unroll
        for (int r = 0; r < 4; r++) {
            int rl = wv * 16 + grp * 4 + r;
            int t = t0 + rl;
            float w = 0.f;
            if (t < len) w = __expf(s[r] - Mabs);
            w_s[rl] = w;
            if (t < T_) wbuf[b * T_ + t] = w;
        }
    }
    __syncthreads();

    // denominator partial (wave 0)
    if (tid < 64) {
        float w = w_s[tid];
        w += __shfl_xor(w, 1, 64);
        w += __shfl_xor(w, 2, 64);
        w += __shfl_xor(w, 4, 64);
        w += __shfl_xor(w, 8, 64);
        w += __shfl_xor(w, 16, 64);
        w += __shfl_xor(w, 32, 64);
        if (tid == 0) atomicAdd(&denom[b], w);
    }

    // context partial: tile rows are L2/L3-hot from the GEMM reads
    int n_eff = len - t0;
    if (n_eff > BT) n_eff = BT;
    if (n_eff > 0) {
        int d0 = tid * 2;
        const float* ebase = input_enc + ((size_t)(b * T_ + t0)) * DE_ + d0;
        float cx = 0.f, cy = 0.f;
        #pragma unroll 8
        for (int t = 0; t < n_eff; t++) {
            float w = w_s[t];
            float2 v = *(const float2*)(ebase + (size_t)t * DE_);
            cx += w * v.x;
            cy += w * v.y;
        }
        atomicAdd(&ctx_un[b * DE_ + d0 + 0], cx);
        atomicAdd(&ctx_un[b * DE_ + d0 + 1], cy);
    }
}

// ---------------------------------------------------------------------------
// Kernel 3: finalize. blocks 0..63: att = wbuf/denom; 64..79: ctx = ctx_un/denom
// ---------------------------------------------------------------------------
__global__ __launch_bounds__(256) void finalize_kernel(
    const float* __restrict__ wbuf, const float* __restrict__ ctx_un,
    const float* __restrict__ denom, float* __restrict__ out)
{
    int bx = blockIdx.x, tid = threadIdx.x;
    if (bx < 64) {
        int i4 = bx * 256 + tid;
        if (i4 < (B_ * T_) / 4) {
            int b = i4 / (T_ / 4);
            float inv = 1.f / denom[b];
            float4 w = ((const float4*)wbuf)[i4];
            w.x *= inv; w.y *= inv; w.z *= inv; w.w *= inv;
            ((float4*)(out + B_ * DE_))[i4] = w;
        }
    } else {
        int j = (bx - 64) * 256 + tid;          // 0..4095
        int b = j / (DE_ / 4);
        float inv = 1.f / denom[b];
        float4 c = ((const float4*)ctx_un)[j];
        c.x *= inv; c.y *= inv; c.z *= inv; c.w *= inv;
        ((float4*)out)[j] = c;
    }
}

// ---------------------------------------------------------------------------
extern "C" void kernel_launch(void* const* d_in, const int* in_sizes, int n_in,
                              void* d_out, int out_size, void* d_ws, size_t ws_size,
                              hipStream_t stream)
{
    const float* input_enc   = (const float*)d_in[0];
    const int*   enc_lengths = (const int*)d_in[1];
    const float* input_dec   = (const float*)d_in[2];
    const float* prev_att    = (const float*)d_in[3];
    const float* conv_w      = (const float*)d_in[4];
    const float* enc_w       = (const float*)d_in[5];
    const float* dec_w       = (const float*)d_in[6];
    const float* att_w       = (const float*)d_in[7];
    const float* att_b       = (const float*)d_in[8];
    const float* out_w       = (const float*)d_in[9];

    float* out = (float*)d_out;                 // [0:B*DE) context, [B*DE:) att_weight
    char* ws = (char*)d_ws;
    float*  pdec   = (float*)ws;                              // 4096 f   (16384 B)
    float*  wbuf   = (float*)(ws + 16384);                    // 64000 f  (256000 B)
    __bf16* enc_bf = (__bf16*)(ws + 272384);                  // A*DE bf16 (131072 B)
    __bf16* att_bf = (__bf16*)(ws + 403456);                  // A*FN bf16 (8192 B)
    float*  ctx_un = (float*)(ws + 411648);                   // 16384 f  (65536 B)
    float*  denom  = (float*)(ws + 477184);                   // 32 f

    prep_kernel<<<209, 256, 0, stream>>>(enc_w, att_w, input_dec, dec_w, att_b,
                                         enc_bf, att_bf, pdec, ctx_un);

    dim3 sgrid((T_ + BT - 1) / BT, B_);
    score_kernel<<<sgrid, 256, 0, stream>>>(input_enc, enc_bf, prev_att, conv_w,
                                            att_bf, pdec, out_w, enc_lengths,
                                            wbuf, ctx_un, denom);

    finalize_kernel<<<80, 256, 0, stream>>>(wbuf, ctx_un, denom, out);
}

// Round 9
// 229.702 us; speedup vs baseline: 1.0199x; 1.0199x over previous
//
#include <hip/hip_runtime.h>
#include <hip/hip_bf16.h>
#include <math.h>

#define B_ 32
#define T_ 2000
#define DE_ 512
#define DD_ 1024
#define A_ 128
#define FN_ 32
#define FS_ 16
#define KW_ (2*FS_+1)   // 33

typedef __bf16 bf16x8 __attribute__((ext_vector_type(8)));
typedef __bf16 bf16x4 __attribute__((ext_vector_type(4)));
typedef float f32x4 __attribute__((ext_vector_type(4)));

#define BT 128           // t-rows per score block (8 waves x 16 rows)
#define LSTR 40          // loc tile LDS stride (bf16)

// async global->LDS, 16 B per lane; dest = lds base (wave-uniform) + lane*16
__device__ __forceinline__ void load_lds16(const void* g, void* l) {
    __builtin_amdgcn_global_load_lds(
        (const __attribute__((address_space(1))) unsigned int*)g,
        (__attribute__((address_space(3))) unsigned int*)l, 16, 0, 0);
}

// volatile asm global load: CANNOT be sunk/reordered by the compiler.
__device__ __forceinline__ f32x4 gload4(const float* p) {
    f32x4 d;
    asm volatile("global_load_dwordx4 %0, %1, off" : "=v"(d) : "v"(p));
    return d;
}

__device__ __forceinline__ bf16x8 cvt8v(f32x4 x, f32x4 y) {
    bf16x8 o;
    o[0] = (__bf16)x[0]; o[1] = (__bf16)x[1]; o[2] = (__bf16)x[2]; o[3] = (__bf16)x[3];
    o[4] = (__bf16)y[0]; o[5] = (__bf16)y[1]; o[6] = (__bf16)y[2]; o[7] = (__bf16)y[3];
    return o;
}

// ---------------------------------------------------------------------------
// Kernel 1: prep.
//  blocks   0..63 : enc_w/att_w fp32->bf16
//  blocks  64..191: pdec[b][a] = att_b[a] + input_dec[b] . dec_w[a]
//  blocks 192..208: zero ctx_un (16384 f) + denom (32 f)
// ---------------------------------------------------------------------------
__global__ __launch_bounds__(256) void prep_kernel(
    const float* __restrict__ enc_w, const float* __restrict__ att_w,
    const float* __restrict__ input_dec, const float* __restrict__ dec_w,
    const float* __restrict__ att_b,
    __bf16* __restrict__ enc_bf, __bf16* __restrict__ att_bf,
    float* __restrict__ pdec, float* __restrict__ ctx_un /* denom follows */)
{
    int bx = blockIdx.x, tid = threadIdx.x;
    if (bx < 64) {
        int i = bx * 256 + tid;                         // float4 index
        float4 v = ((const float4*)enc_w)[i];
        bf16x4 o;
        o[0] = (__bf16)v.x; o[1] = (__bf16)v.y; o[2] = (__bf16)v.z; o[3] = (__bf16)v.w;
        *(bf16x4*)(enc_bf + (size_t)i * 4) = o;
        if (i < (A_ * FN_) / 4) {
            float4 w = ((const float4*)att_w)[i];
            bf16x4 p;
            p[0] = (__bf16)w.x; p[1] = (__bf16)w.y; p[2] = (__bf16)w.z; p[3] = (__bf16)w.w;
            *(bf16x4*)(att_bf + (size_t)i * 4) = p;
        }
    } else if (bx < 192) {
        int pb = bx - 64;                               // 0..127
        int b  = pb >> 2;
        int a0 = (pb & 3) * 32;
        int al = tid >> 3;                              // 0..31
        int kg = tid & 7;                               // 0..7
        int a  = a0 + al;
        const float4* w = (const float4*)(dec_w + (size_t)a * DD_);
        const float4* x = (const float4*)(input_dec + (size_t)b * DD_);
        float acc = 0.f;
        #pragma unroll 8
        for (int j = 0; j < 32; j++) {
            int i4 = kg + j * 8;
            float4 wv = w[i4], xv = x[i4];
            acc += wv.x * xv.x + wv.y * xv.y + wv.z * xv.z + wv.w * xv.w;
        }
        acc += __shfl_xor(acc, 1, 64);
        acc += __shfl_xor(acc, 2, 64);
        acc += __shfl_xor(acc, 4, 64);
        if (kg == 0) pdec[b * A_ + a] = acc + att_b[a];
    } else {
        int idx = (bx - 192) * 256 + tid;               // float4 index
        if (idx < (B_ * DE_ + B_) / 4 + 1)              // 16416 floats -> 4104 f4
            ((float4*)ctx_un)[idx] = make_float4(0.f, 0.f, 0.f, 0.f);
    }
}

// ---------------------------------------------------------------------------
// Kernel 2: score + context partials. One block = (b, 128 t-rows), 512 thr
// = 8 waves, 1 block/CU (LDS 142.5 KB). Combines r4's barrier-free K-loop
// (whole B staged to LDS ONCE) with a per-wave REGISTER pipeline of A built
// from volatile-asm global_load_dwordx4 (cannot be sunk -> 4 chunks / 8
// loads guaranteed in flight per wave) waited by counted s_waitcnt vmcnt(N)
// whose asm ties the destination regs ("+v") so consumption is dataflow-
// ordered after the wait. ZERO barriers in the K-loop: waves free-run,
// HBM latency hidden by per-wave ILP. Grid 512 blocks -> masked blocks
// early-exit and the CU backfills with the next block (load balance).
// K order identical to prior rounds -> bit-identical output.
// Max-free softmax: w = exp(score - M), M = sum|out_w|. Block accumulates
// its 128x512 tile into ctx_un + denom.
// ---------------------------------------------------------------------------
__global__ __launch_bounds__(512, 1) void score_kernel(
    const float* __restrict__ input_enc, const __bf16* __restrict__ enc_bf,
    const float* __restrict__ prev_att,  const float* __restrict__ conv_w,
    const __bf16* __restrict__ att_bf,   const float* __restrict__ pdec,
    const float* __restrict__ out_w,     const int* __restrict__ lengths,
    float* __restrict__ wbuf, float* __restrict__ ctx_un,
    float* __restrict__ denom)
{
    __shared__ __align__(16) char BtAll[8][16384]; // full B: 8 chunks x 128 rows x 64 col bf16
    __shared__ __align__(16) float pa_s[BT + 2 * FS_];
    __shared__ __align__(16) __bf16 loc_s[BT * LSTR];
    __shared__ float w_s[BT];

    const int tid  = threadIdx.x;
    const int lane = tid & 63;
    const int wv   = tid >> 6;                   // 0..7
    const int b  = blockIdx.y;
    const int t0 = blockIdx.x * BT;
    const int len = lengths[b];

    // ---- early exit: block entirely past this utterance's length ----
    if (t0 >= len) {
        if (tid < BT) {
            int t = t0 + tid;
            if (t < T_) wbuf[b * T_ + t] = 0.f;
        }
        return;
    }

    const int col  = lane & 15;
    const int grp  = lane >> 4;
    const int rowb = wv * 16 + col;              // 0..127
    const int t_row = t0 + rowb;
    const int t_clamp = t_row < T_ ? t_row : T_ - 1;
    const int sw = (col & 7);                    // B-read swizzle key

    const float* arow = input_enc + ((size_t)(b * T_ + t_clamp)) * DE_ + grp * 8;

    // ---- A prologue: issue chunks 0..3 (8 asm loads; drained by barrier,
    //      so chunks 0..3 are ready at K-loop start = free prefetch)
    f32x4 pipe[4][2];
    #pragma unroll
    for (int c2 = 0; c2 < 4; c2++) {
        pipe[c2][0] = gload4(arow + c2 * 32);
        pipe[c2][1] = gload4(arow + c2 * 32 + 4);
    }

    // ---- stage ALL of B into LDS (async, XOR-8 source swizzle)
    #pragma unroll
    for (int j = 0; j < 8; j++) {
        #pragma unroll
        for (int jj = 0; jj < 2; jj++) {
            int s  = jj * 512 + tid;             // granule 0..1023 in chunk
            int r  = s >> 3;                     // row 0..127
            int cp = s & 7;                      // phys 16B granule in 128B row
            int c  = cp ^ (r & 7);               // XOR swizzle (source side)
            load_lds16(enc_bf + (size_t)r * DE_ + j * 64 + c * 8,
                       (char*)BtAll + j * 16384 + jj * 8192 + wv * 1024);
        }
    }

    // conv weights for this thread's filter f: direct from global (L1-hot)
    const int f    = tid & 31;
    const int rblk = tid >> 5;                   // 0..15 -> rows rblk*8..+7
    float cwr[KW_];
    #pragma unroll
    for (int k = 0; k < KW_; k++) cwr[k] = conv_w[f * KW_ + k];

    if (tid < BT + 2 * FS_) {
        int t = t0 - FS_ + tid;
        pa_s[tid] = (t >= 0 && t < T_) ? prev_att[b * T_ + t] : 0.f;
    }
    __syncthreads();                             // pa_s ready; B + A0..3 drained

    {   // conv -> loc (bf16), register-blocked: 8 consecutive rows per thread
        float par[40];
        #pragma unroll
        for (int j = 0; j < 10; j++)
            *(float4*)&par[j * 4] = *(const float4*)&pa_s[rblk * 8 + j * 4];
        float accv[8] = {0.f, 0.f, 0.f, 0.f, 0.f, 0.f, 0.f, 0.f};
        #pragma unroll
        for (int k = 0; k < KW_; k++) {
            float c = cwr[k];
            #pragma unroll
            for (int j = 0; j < 8; j++) accv[j] += par[j + k] * c;
        }
        #pragma unroll
        for (int j = 0; j < 8; j++)
            loc_s[(rblk * 8 + j) * LSTR + f] = (__bf16)accv[j];
    }
    __syncthreads();                             // loc_s ready (LAST barrier before epilogue)

    f32x4 acc[8];
    const f32x4 zero = (f32x4){0.f, 0.f, 0.f, 0.f};

    {   // loc-projection MFMA (K=32=FN)
        bf16x8 afrag = *(const bf16x8*)(loc_s + rowb * LSTR + grp * 8);
        #pragma unroll
        for (int i = 0; i < 8; i++) {
            bf16x8 bfrag = *(const bf16x8*)(att_bf + (size_t)(i * 16 + col) * FN_ + grp * 8);
            acc[i] = __builtin_amdgcn_mfma_f32_16x16x32_bf16(afrag, bfrag, zero, 0, 0, 0);
        }
    }

    // ---- barrier-free K-loop: 16 x 32-col steps; per-wave asm pipeline.
    // Wait count at step IT: outstanding = chunks IT..min(15,IT+3) (2 loads
    // each, issues trail by 4); steady vmcnt(6), tail 6/4/2/0.
#define KSTEP(IT, CNT) { \
    asm volatile("s_waitcnt vmcnt(" #CNT ")" \
                 : "+v"(pipe[(IT) % 4][0]), "+v"(pipe[(IT) % 4][1])); \
    bf16x8 af = cvt8v(pipe[(IT) % 4][0], pipe[(IT) % 4][1]); \
    const char* Bb = (const char*)BtAll + ((IT) >> 1) * 16384; \
    _Pragma("unroll") \
    for (int i = 0; i < 8; i++) { \
        bf16x8 bfrag = *(const bf16x8*)(Bb + (i * 16 + col) * 128 + \
                                        ((((IT) & 1) * 4 + grp) ^ sw) * 16); \
        acc[i] = __builtin_amdgcn_mfma_f32_16x16x32_bf16(af, bfrag, acc[i], 0, 0, 0); \
    } \
    if ((IT) + 4 <= 15) { \
        pipe[(IT) % 4][0] = gload4(arow + ((IT) + 4) * 32); \
        pipe[(IT) % 4][1] = gload4(arow + ((IT) + 4) * 32 + 4); \
    } \
}
    KSTEP(0, 6)  KSTEP(1, 6)  KSTEP(2, 6)  KSTEP(3, 6)
    KSTEP(4, 6)  KSTEP(5, 6)  KSTEP(6, 6)  KSTEP(7, 6)
    KSTEP(8, 6)  KSTEP(9, 6)  KSTEP(10, 6) KSTEP(11, 6)
    KSTEP(12, 6) KSTEP(13, 4) KSTEP(14, 2) KSTEP(15, 0)
#undef KSTEP

    // epilogue: s = tanh(acc + bias) . out_w over a; M = sum|out_w|
    float s[4] = {0.f, 0.f, 0.f, 0.f};
    float Mabs = 0.f;
    #pragma unroll
    for (int i = 0; i < 8; i++) {
        int a = i * 16 + col;
        float ow = out_w[a];
        Mabs += fabsf(ow);
        float bias = pdec[b * A_ + a];
        #pragma unroll
        for (int r = 0; r < 4; r++) {
            float v = acc[i][r] + bias;
            v = fminf(fmaxf(v, -15.f), 15.f);
            float e = __expf(2.f * v);
            s[r] += ow * ((e - 1.f) / (e + 1.f));
        }
    }
    #pragma unroll
    for (int r = 0; r < 4; r++) {
        s[r] += __shfl_xor(s[r], 1, 64);
        s[r] += __shfl_xor(s[r], 2, 64);
        s[r] += __shfl_xor(s[r], 4, 64);
        s[r] += __shfl_xor(s[r], 8, 64);
    }
    Mabs += __shfl_xor(Mabs, 1, 64);
    Mabs += __shfl_xor(Mabs, 2, 64);
    Mabs += __shfl_xor(Mabs, 4, 64);
    Mabs += __shfl_xor(Mabs, 8, 64);    // same value & rounding in every wave

    if (col == 0) {
        #pragma unroll
        for (int r = 0; r < 4; r++) {
            int rl = wv * 16 + grp * 4 + r;
            int t = t0 + rl;
            float w = 0.f;
            if (t < len) w = __expf(s[r] - Mabs);
            w_s[rl] = w;
            if (t < T_) wbuf[b * T_ + t] = w;
        }
    }
    __syncthreads();                             // w_s ready

    // denominator partial (wave 0 reduces all 128)
    if (tid < 64) {
        float w = w_s[tid] + w_s[tid + 64];
        w += __shfl_xor(w, 1, 64);
        w += __shfl_xor(w, 2, 64);
        w += __shfl_xor(w, 4, 64);
        w += __shfl_xor(w, 8, 64);
        w += __shfl_xor(w, 16, 64);
        w += __shfl_xor(w, 32, 64);
        if (tid == 0) atomicAdd(&denom[b], w);
    }

    // context partial: 512 threads x 1 d-col each; tile rows L2/L3-hot
    int n_eff = len - t0;
    if (n_eff > BT) n_eff = BT;
    if (n_eff > 0) {
        int d0 = tid;                            // 0..511
        const float* ebase = input_enc + ((size_t)(b * T_ + t0)) * DE_ + d0;
        float cx = 0.f;
        #pragma unroll 8
        for (int t = 0; t < n_eff; t++)
            cx += w_s[t] * ebase[(size_t)t * DE_];
        atomicAdd(&ctx_un[b * DE_ + d0], cx);
    }
}

// ---------------------------------------------------------------------------
// Kernel 3: finalize. blocks 0..63: att = wbuf/denom; 64..79: ctx = ctx_un/denom
// ---------------------------------------------------------------------------
__global__ __launch_bounds__(256) void finalize_kernel(
    const float* __restrict__ wbuf, const float* __restrict__ ctx_un,
    const float* __restrict__ denom, float* __restrict__ out)
{
    int bx = blockIdx.x, tid = threadIdx.x;
    if (bx < 64) {
        int i4 = bx * 256 + tid;
        if (i4 < (B_ * T_) / 4) {
            int b = i4 / (T_ / 4);
            float inv = 1.f / denom[b];
            float4 w = ((const float4*)wbuf)[i4];
            w.x *= inv; w.y *= inv; w.z *= inv; w.w *= inv;
            ((float4*)(out + B_ * DE_))[i4] = w;
        }
    } else {
        int j = (bx - 64) * 256 + tid;          // 0..4095
        int b = j / (DE_ / 4);
        float inv = 1.f / denom[b];
        float4 c = ((const float4*)ctx_un)[j];
        c.x *= inv; c.y *= inv; c.z *= inv; c.w *= inv;
        ((float4*)out)[j] = c;
    }
}

// ---------------------------------------------------------------------------
extern "C" void kernel_launch(void* const* d_in, const int* in_sizes, int n_in,
                              void* d_out, int out_size, void* d_ws, size_t ws_size,
                              hipStream_t stream)
{
    const float* input_enc   = (const float*)d_in[0];
    const int*   enc_lengths = (const int*)d_in[1];
    const float* input_dec   = (const float*)d_in[2];
    const float* prev_att    = (const float*)d_in[3];
    const float* conv_w      = (const float*)d_in[4];
    const float* enc_w       = (const float*)d_in[5];
    const float* dec_w       = (const float*)d_in[6];
    const float* att_w       = (const float*)d_in[7];
    const float* att_b       = (const float*)d_in[8];
    const float* out_w       = (const float*)d_in[9];

    float* out = (float*)d_out;                 // [0:B*DE) context, [B*DE:) att_weight
    char* ws = (char*)d_ws;
    float*  pdec   = (float*)ws;                              // 4096 f   (16384 B)
    float*  wbuf   = (float*)(ws + 16384);                    // 64000 f  (256000 B)
    __bf16* enc_bf = (__bf16*)(ws + 272384);                  // A*DE bf16 (131072 B)
    __bf16* att_bf = (__bf16*)(ws + 403456);                  // A*FN bf16 (8192 B)
    float*  ctx_un = (float*)(ws + 411648);                   // 16384 f  (65536 B)
    float*  denom  = (float*)(ws + 477184);                   // 32 f

    prep_kernel<<<209, 256, 0, stream>>>(enc_w, att_w, input_dec, dec_w, att_b,
                                         enc_bf, att_bf, pdec, ctx_un);

    dim3 sgrid((T_ + BT - 1) / BT, B_);
    score_kernel<<<sgrid, 512, 0, stream>>>(input_enc, enc_bf, prev_att, conv_w,
                                            att_bf, pdec, out_w, enc_lengths,
                                            wbuf, ctx_un, denom);

    finalize_kernel<<<80, 256, 0, stream>>>(wbuf, ctx_un, denom, out);
}